// Round 11
// baseline (67.173 us; speedup 1.0000x reference)
//
#include <hip/hip_runtime.h>
#include <hip/hip_bf16.h>
#include <float.h>

// GraphSAGE: masked-max agg + ReLU + concat + Linear(256->128).
// B=4, N=512, C=128, OUT=128.
//
// R11: R10's sync-free single-dispatch fusion, but 4 waves/node instead of 2:
//   grid = 512 blocks x 1024 thr (16 waves) -> 2 blocks/CU = 32 waves/CU
//   (R7-agg occupancy), and each wave scans a QUARTER row (~13 nbrs -> 2
//   serial 8-wide gather rounds instead of 4). Block owns 4 output rows;
//   MFMA tile is 4/16 valid (waste irrelevant: 8 MFMA instrs/wave).
//   phase A: wave w -> slot w&3, quarter w>>2. Ballot-compact, pad to x8
//            (dup; max idempotent), 8-wide gather rounds. pm -> LDS.
//   phase B: waves 0-3 combine 4 partials, relu, + self -> bf16 A rows 0-3
//            (rows 4-15 zero). Waves 0-7: n-tile w MFMA, B-frag from L2-hot
//            fp32 W, bias, store rows 0-3.
// R8/R9 lesson intact: zero inter-block sync (device fences nuke per-XCD L2).

#define Bsz 4
#define Nn  512
#define Cc  128
#define OUTn 128
#define NNODES (Bsz * Nn)   // 2048
#define KK (2 * Cc)         // 256
#define ROWP 264            // LDS A-tile row stride (bf16): +8 -> bank skew

typedef __bf16 bf16x8 __attribute__((ext_vector_type(8)));
typedef float  f32x4  __attribute__((ext_vector_type(4)));

static __device__ __forceinline__ unsigned short f2bf(float x) {
    __hip_bfloat16 h = __float2bfloat16(x);
    return *reinterpret_cast<unsigned short*>(&h);
}
static __device__ __forceinline__ __bf16 f2bf16(float x) {
    unsigned short u = f2bf(x);
    return *reinterpret_cast<__bf16*>(&u);
}

__global__ __launch_bounds__(1024, 8) void sage_fused(
    const float* __restrict__ adj,
    const float* __restrict__ feat,
    const float* __restrict__ W,      // fp32 [256][128]
    const float* __restrict__ bias,   // fp32 [128]
    float* __restrict__ out)          // fp32 [2048][128]
{
    const int bid = blockIdx.x;       // 0..511, owns nodes bid*4 .. +3
    const int w = threadIdx.x >> 6;   // 0..15
    const int l = threadIdx.x & 63;

    __shared__ unsigned short nbr[16][128];  // per-wave compacted quarter-row
    __shared__ float2 pm[16][64];            // per-wave partial maxima
    __shared__ unsigned short sA[16][ROWP];  // bf16 A-tile (rows 4..15 = 0)

    const int slot = w & 3;                  // node slot within the 4 rows
    const int q    = w >> 2;                 // adjacency quarter [128q,+128)
    const int node = bid * 4 + slot;
    const int b = node >> 9;
    const int i = node & (Nn - 1);

    // ---- phase A: ballot-compact + 8-wide max-gather of a quarter row ----
    const float* adjrow = adj + (size_t)node * Nn;
    const float2* f2 = (const float2*)(feat + (size_t)b * Nn * Cc);

    int cnt = 0;
    #pragma unroll
    for (int ch = 0; ch < 2; ++ch) {
        int j = q * 128 + ch * 64 + l;
        float a = adjrow[j];
        unsigned long long mask = __ballot(a > 0.0f);
        int pos = __popcll(mask & ((1ull << l) - 1ull));
        if (a > 0.0f) nbr[w][cnt + pos] = (unsigned short)j;
        cnt += __popcll(mask);
    }
    // Pad to a multiple of 8 with a duplicate (max is idempotent).
    if (cnt > 0) {
        unsigned short p0 = nbr[w][0];
        int padded = (cnt + 7) & ~7;
        if (l < padded - cnt) nbr[w][cnt + l] = p0;
        cnt = padded;
    }
    // Same-wave DS write->read: lgkmcnt ordering guarantees visibility.

    float m0 = -FLT_MAX, m1 = -FLT_MAX;
    for (int k = 0; k < cnt; k += 8) {
        int j0 = nbr[w][k + 0], j1 = nbr[w][k + 1];
        int j2 = nbr[w][k + 2], j3 = nbr[w][k + 3];
        int j4 = nbr[w][k + 4], j5 = nbr[w][k + 5];
        int j6 = nbr[w][k + 6], j7 = nbr[w][k + 7];
        float2 v0 = f2[j0 * 64 + l];
        float2 v1 = f2[j1 * 64 + l];
        float2 v2 = f2[j2 * 64 + l];
        float2 v3 = f2[j3 * 64 + l];
        float2 v4 = f2[j4 * 64 + l];
        float2 v5 = f2[j5 * 64 + l];
        float2 v6 = f2[j6 * 64 + l];
        float2 v7 = f2[j7 * 64 + l];
        m0 = fmaxf(m0, fmaxf(fmaxf(fmaxf(v0.x, v1.x), fmaxf(v2.x, v3.x)),
                             fmaxf(fmaxf(v4.x, v5.x), fmaxf(v6.x, v7.x))));
        m1 = fmaxf(m1, fmaxf(fmaxf(fmaxf(v0.y, v1.y), fmaxf(v2.y, v3.y)),
                             fmaxf(fmaxf(v4.y, v5.y), fmaxf(v6.y, v7.y))));
    }
    pm[w][l] = make_float2(m0, m1);

    // Zero A-tile rows 4..15 (12 * 132 dwords) with the whole block.
    {
        unsigned int* z = (unsigned int*)&sA[4][0];
        for (int idx = threadIdx.x; idx < 12 * (ROWP / 2); idx += 1024) z[idx] = 0u;
    }
    __syncthreads();

    // ---- combine quarters, relu, self row -> bf16 A-tile rows 0..3 ----
    if (w < 4) {   // w<4 => q==0 => node/i above are this slot's node
        float2 a0 = pm[w][l], a1 = pm[w + 4][l];
        float2 a2 = pm[w + 8][l], a3 = pm[w + 12][l];
        // relu(max) also maps no-neighbor (-FLT_MAX) to 0, matching the
        // reference (finfo.min is finite; its isfinite-guard never fires).
        float n0 = fmaxf(fmaxf(fmaxf(a0.x, a1.x), fmaxf(a2.x, a3.x)), 0.0f);
        float n1 = fmaxf(fmaxf(fmaxf(a0.y, a1.y), fmaxf(a2.y, a3.y)), 0.0f);
        float2 s = f2[i * 64 + l];

        ushort2* crow = (ushort2*)&sA[w][0];
        ushort2 sv; sv.x = f2bf(s.x); sv.y = f2bf(s.y);
        ushort2 nv; nv.x = f2bf(n0);  nv.y = f2bf(n1);
        crow[l]      = sv;   // self  ch [2l, 2l+1]
        crow[64 + l] = nv;   // neigh ch [128+2l, 128+2l+1]
    }
    __syncthreads();

    // ---- phase B: wave w (<8) computes n-tile nt=w for rows 0..3 ----
    // A-frag: lane holds A[m=l&15][k=koff+j] -> ds_read_b128 from sA.
    // B-frag: lane holds B[k=koff+j][n=nt*16+(l&15)] from fp32 W + cvt.
    // C/D: col = lane&15, row = (lane>>4)*4 + reg   [measured m89/m91]
    if (w < 8) {
        const int nt = w;
        const int frow = l & 15;
        const int koff = (l >> 4) * 8;
        const float* wp = W + nt * 16 + frow;   // stride OUTn over k

        f32x4 acc = {0.f, 0.f, 0.f, 0.f};
        #pragma unroll
        for (int ks = 0; ks < KK / 32; ++ks) {
            bf16x8 af = *(const bf16x8*)&sA[frow][ks * 32 + koff];
            bf16x8 bfr;
            #pragma unroll
            for (int j = 0; j < 8; ++j) {
                bfr[j] = f2bf16(wp[(size_t)(ks * 32 + koff + j) * OUTn]);
            }
            acc = __builtin_amdgcn_mfma_f32_16x16x32_bf16(af, bfr, acc, 0, 0, 0);
        }

        const int col = l & 15;
        const int r0  = (l >> 4) * 4;    // only r0==0 lanes hold valid rows
        const float bv = bias[nt * 16 + col];
        #pragma unroll
        for (int r = 0; r < 4; ++r) {
            int row = r0 + r;
            if (row < 4) {
                out[(size_t)(bid * 4 + row) * OUTn + nt * 16 + col]
                    = acc[r] + bv;
            }
        }
    }
}

extern "C" void kernel_launch(void* const* d_in, const int* in_sizes, int n_in,
                              void* d_out, int out_size, void* d_ws, size_t ws_size,
                              hipStream_t stream) {
    const float* adj  = (const float*)d_in[0];
    const float* feat = (const float*)d_in[1];
    const float* W    = (const float*)d_in[2];
    const float* bias = (const float*)d_in[3];
    float* out = (float*)d_out;

    sage_fused<<<dim3(NNODES / 4), dim3(1024), 0, stream>>>(
        adj, feat, W, bias, out);
}